// Round 17
// baseline (136.807 us; speedup 1.0000x reference)
//
#include <hip/hip_runtime.h>

#define SEQ 200
#define HID 64
#define BT  16
#define NBLK (4096 / BT)   // 256 blocks -> 1 per CU, 4 waves, 2-group pipeline

typedef _Float16 f16;
typedef _Float16 f16x8 __attribute__((ext_vector_type(8)));
typedef float    f32x4 __attribute__((ext_vector_type(4)));

#define LOG2E 1.44269504088896340736f

#if __has_builtin(__builtin_amdgcn_exp2f)
#define EXP2F(x) __builtin_amdgcn_exp2f(x)
#else
#define EXP2F(x) __expf(0.69314718056f * (x))
#endif
#define RCPF(x) __builtin_amdgcn_rcpf(x)

// v17: two-group software pipeline on the R14 base (84.5us proven).
//  - BT=16/block, grid 256 (1 block/CU, 4 waves). G0 = block rows 0..7,
//    G1 = rows 8..15. Each group is EXACTLY R14's 8-row sigma-mapped GEMM
//    (frag row r <-> group row 2*(r>>2)+(r&1); lane group a owns group rows
//    2a, 2a+1 in C regs 0,1; h written only to frag rows 4a, 4a+1; rows
//    4a+2,3 stay zero; shared-rcp trans 5exp+3rcp/cell).
//  - Phase schedule per step t:
//      [MFMA G1(t) || pointwise G0(t)->h0(t+1)]  barrier
//      [MFMA G0(t+1) || pointwise G1(t)->h1(t+1)] barrier
//    Gates stay in registers across one phase (lane-local by sigma-mapping);
//    each group's barrier drain + MFMA latency hides under the OTHER group's
//    trans chain. 2 barriers/step but zero exposed-chain by construction.
//  - 1 wave/SIMD -> no setprio (nothing to arbitrate).
__global__ __launch_bounds__(256, 1)
void qlstm_v17(const float* __restrict__ x,      // [4096, 200]
               const float* __restrict__ W_ih,   // [256]
               const float* __restrict__ W_hh,   // [256, 64]
               const float* __restrict__ b_ih,   // [256]
               const float* __restrict__ b_hh,   // [256]
               const float* __restrict__ W_lin,  // [200*64]
               const float* __restrict__ b_lin,  // [1]
               float* __restrict__ out)          // [4096]
{
    __shared__ float x_lds[BT][201];           // 12.9 KB
    __shared__ f16   h_frag[2][2][16 * HID];   // [group][buf], 8 KB, swizzled
    __shared__ float wl_lds[SEQ * HID];        // 51.2 KB
    __shared__ float out_part[4][BT];

    const int tid = threadIdx.x;
    const int w   = tid >> 6;     // wave: j-block owner
    const int l   = tid & 63;
    const int m   = l & 15;       // B col / C col
    const int a   = l >> 4;       // k-group / C row-group
    const int b0  = blockIdx.x * BT;

    // quadrant pre-scales: i,f,o -> log2e ; g -> 2*log2e
    const float qs[4] = {LOG2E, LOG2E, 2.0f * LOG2E, LOG2E};

    // ---- stage x rows 0..15 (f32, coalesced) ----
    for (int i = tid; i < BT * SEQ; i += 256) {
        int b = i / SEQ, t = i - b * SEQ;
        x_lds[b][t] = x[(size_t)b0 * SEQ + i];
    }
    // ---- stage W_lin (float4) ----
    {
        const float4* src = (const float4*)W_lin;
        float4* dst = (float4*)wl_lds;
        for (int i = tid; i < SEQ * HID / 4; i += 256) dst[i] = src[i];
    }
    // ---- zero all h buffers (rows == 2,3 mod 4 stay zero forever) ----
    for (int i = tid; i < 2048; i += 256) ((float*)h_frag)[i] = 0.0f;

    // ---- B fragments (W_hh^T, pre-scaled) once: col n=q*64+16w+m, k=kk*32+a*8+e ----
    f16x8 Bf[4][2];
    float wihq[4], biasq[4];
    #pragma unroll
    for (int q = 0; q < 4; ++q) {
        const int n = q * 64 + w * 16 + m;
        wihq[q]  = W_ih[n] * qs[q];
        biasq[q] = (b_ih[n] + b_hh[n]) * qs[q];
        #pragma unroll
        for (int kk = 0; kk < 2; ++kk) {
            const float4* p = (const float4*)(W_hh + n * HID + kk * 32 + a * 8);
            float4 lo = p[0], hi = p[1];
            f16x8 f;
            f[0] = (f16)(lo.x * qs[q]); f[1] = (f16)(lo.y * qs[q]);
            f[2] = (f16)(lo.z * qs[q]); f[3] = (f16)(lo.w * qs[q]);
            f[4] = (f16)(hi.x * qs[q]); f[5] = (f16)(hi.y * qs[q]);
            f[6] = (f16)(hi.z * qs[q]); f[7] = (f16)(hi.w * qs[q]);
            Bf[q][kk] = f;
        }
    }

    const int jpw = w * 16 + m;
    // A-frag read addrs within one 2KB buffer (R14 formulas):
    const int ra0 = m * 128 + (((0 + a) ^ (m & 7)) << 4);
    const int ra1 = m * 128 + (((4 + a) ^ (m & 7)) << 4);
    // h write addrs within one buffer: rows 4a (cell A), 4a+1 (cell B)
    const int R0 = 4 * a, R1 = 4 * a + 1;
    const int hwA = R0 * 128 + (((jpw >> 3) ^ (R0 & 7)) << 4) + (jpw & 7) * 2;
    const int hwB = R1 * 128 + (((jpw >> 3) ^ (R1 & 7)) << 4) + (jpw & 7) * 2;

    // group-local batch rows for this lane
    const int r0A = 2 * a,     r0B = 2 * a + 1;       // G0 block rows
    const int r1A = 8 + 2 * a, r1B = 8 + 2 * a + 1;   // G1 block rows

    const char* hb = (const char*)h_frag;   // G0 at +0, G1 at +4096; buf at +2048*p

    float c0A = 0.f, c0B = 0.f, c1A = 0.f, c1B = 0.f;
    float o0A = 0.f, o0B = 0.f, o1A = 0.f, o1B = 0.f;
    const float t2s = 2.0f * LOG2E;

    f32x4 acc0[4], acc1[4];

    // gate GEMM for one group (R14's chained-pair form, 8 MFMAs)
    auto GATE = [&](f32x4 (&acc)[4], const int rbyte, const float xa, const float xb) {
        const f16x8 A0 = *(const f16x8*)(hb + rbyte + ra0);
        const f16x8 A1 = *(const f16x8*)(hb + rbyte + ra1);
        #pragma unroll
        for (int q = 0; q < 4; ++q) {
            const float i0 = fmaf(xa, wihq[q], biasq[q]);
            const float i1 = fmaf(xb, wihq[q], biasq[q]);
            f32x4 ini;
            ini[0] = i0; ini[1] = i1; ini[2] = i0; ini[3] = i1;
            f32x4 z = __builtin_amdgcn_mfma_f32_16x16x32_f16(A0, Bf[q][0], ini, 0, 0, 0);
            acc[q]  = __builtin_amdgcn_mfma_f32_16x16x32_f16(A1, Bf[q][1], z, 0, 0, 0);
        }
    };

    __syncthreads();   // staging + zero-init visible

    // ---- prologue: MFMA G0(0) from h0 buf0 (zeros) ----
    GATE(acc0, 0, x_lds[r0A][0], x_lds[r0B][0]);

    for (int t = 0; t < SEQ - 1; ++t) {
        const int p  = t & 1;
        const int pn = p ^ 1;
        const float wl = wl_lds[t * HID + jpw];

        __syncthreads();   // h1(t) visible (t=0: init zeros)

        // ======== phase B: MFMA G1(t)  ||  pointwise G0(t) ========
        GATE(acc1, 4096 + p * 2048, x_lds[r1A][t], x_lds[r1B][t]);
        {
            const float eA = EXP2F(-acc0[0][0]);
            const float eC = EXP2F(-acc0[1][0]);
            const float eB = EXP2F(acc0[2][0]);
            const float eE = EXP2F(-acc0[3][0]);
            const float ig = (eB - 1.0f) * RCPF((1.0f + eA) * (eB + 1.0f));
            const float gf = RCPF(1.0f + eC);
            c0A = fmaf(gf, c0A, t2s * ig);
            const float eD = EXP2F(c0A);
            const float h  = (eD - 1.0f) * RCPF((1.0f + eE) * (eD + 1.0f));
            *(f16*)((char*)h_frag + pn * 2048 + hwA) = (f16)h;
            o0A = fmaf(h, wl, o0A);
        }
        {
            const float eA = EXP2F(-acc0[0][1]);
            const float eC = EXP2F(-acc0[1][1]);
            const float eB = EXP2F(acc0[2][1]);
            const float eE = EXP2F(-acc0[3][1]);
            const float ig = (eB - 1.0f) * RCPF((1.0f + eA) * (eB + 1.0f));
            const float gf = RCPF(1.0f + eC);
            c0B = fmaf(gf, c0B, t2s * ig);
            const float eD = EXP2F(c0B);
            const float h  = (eD - 1.0f) * RCPF((1.0f + eE) * (eD + 1.0f));
            *(f16*)((char*)h_frag + pn * 2048 + hwB) = (f16)h;
            o0B = fmaf(h, wl, o0B);
        }

        __syncthreads();   // h0(t+1) visible

        // ======== phase A: MFMA G0(t+1)  ||  pointwise G1(t) ========
        GATE(acc0, pn * 2048, x_lds[r0A][t + 1], x_lds[r0B][t + 1]);
        {
            const float eA = EXP2F(-acc1[0][0]);
            const float eC = EXP2F(-acc1[1][0]);
            const float eB = EXP2F(acc1[2][0]);
            const float eE = EXP2F(-acc1[3][0]);
            const float ig = (eB - 1.0f) * RCPF((1.0f + eA) * (eB + 1.0f));
            const float gf = RCPF(1.0f + eC);
            c1A = fmaf(gf, c1A, t2s * ig);
            const float eD = EXP2F(c1A);
            const float h  = (eD - 1.0f) * RCPF((1.0f + eE) * (eD + 1.0f));
            *(f16*)((char*)h_frag + 4096 + pn * 2048 + hwA) = (f16)h;
            o1A = fmaf(h, wl, o1A);
        }
        {
            const float eA = EXP2F(-acc1[0][1]);
            const float eC = EXP2F(-acc1[1][1]);
            const float eB = EXP2F(acc1[2][1]);
            const float eE = EXP2F(-acc1[3][1]);
            const float ig = (eB - 1.0f) * RCPF((1.0f + eA) * (eB + 1.0f));
            const float gf = RCPF(1.0f + eC);
            c1B = fmaf(gf, c1B, t2s * ig);
            const float eD = EXP2F(c1B);
            const float h  = (eD - 1.0f) * RCPF((1.0f + eE) * (eD + 1.0f));
            *(f16*)((char*)h_frag + 4096 + pn * 2048 + hwB) = (f16)h;
            o1B = fmaf(h, wl, o1B);
        }
        // next loop-top barrier covers h1(t+1) visibility
    }

    // ---- epilogue: t = SEQ-1 (no h writes needed) ----
    {
        const int t = SEQ - 1;
        const int p = t & 1;
        const float wl = wl_lds[t * HID + jpw];

        __syncthreads();   // h1(SEQ-1) visible
        GATE(acc1, 4096 + p * 2048, x_lds[r1A][t], x_lds[r1B][t]);
        {
            const float eA = EXP2F(-acc0[0][0]);
            const float eC = EXP2F(-acc0[1][0]);
            const float eB = EXP2F(acc0[2][0]);
            const float eE = EXP2F(-acc0[3][0]);
            const float ig = (eB - 1.0f) * RCPF((1.0f + eA) * (eB + 1.0f));
            const float gf = RCPF(1.0f + eC);
            c0A = fmaf(gf, c0A, t2s * ig);
            const float eD = EXP2F(c0A);
            const float h  = (eD - 1.0f) * RCPF((1.0f + eE) * (eD + 1.0f));
            o0A = fmaf(h, wl, o0A);
        }
        {
            const float eA = EXP2F(-acc0[0][1]);
            const float eC = EXP2F(-acc0[1][1]);
            const float eB = EXP2F(acc0[2][1]);
            const float eE = EXP2F(-acc0[3][1]);
            const float ig = (eB - 1.0f) * RCPF((1.0f + eA) * (eB + 1.0f));
            const float gf = RCPF(1.0f + eC);
            c0B = fmaf(gf, c0B, t2s * ig);
            const float eD = EXP2F(c0B);
            const float h  = (eD - 1.0f) * RCPF((1.0f + eE) * (eD + 1.0f));
            o0B = fmaf(h, wl, o0B);
        }
        {
            const float eA = EXP2F(-acc1[0][0]);
            const float eC = EXP2F(-acc1[1][0]);
            const float eB = EXP2F(acc1[2][0]);
            const float eE = EXP2F(-acc1[3][0]);
            const float ig = (eB - 1.0f) * RCPF((1.0f + eA) * (eB + 1.0f));
            const float gf = RCPF(1.0f + eC);
            c1A = fmaf(gf, c1A, t2s * ig);
            const float eD = EXP2F(c1A);
            const float h  = (eD - 1.0f) * RCPF((1.0f + eE) * (eD + 1.0f));
            o1A = fmaf(h, wl, o1A);
        }
        {
            const float eA = EXP2F(-acc1[0][1]);
            const float eC = EXP2F(-acc1[1][1]);
            const float eB = EXP2F(acc1[2][1]);
            const float eE = EXP2F(-acc1[3][1]);
            const float ig = (eB - 1.0f) * RCPF((1.0f + eA) * (eB + 1.0f));
            const float gf = RCPF(1.0f + eC);
            c1B = fmaf(gf, c1B, t2s * ig);
            const float eD = EXP2F(c1B);
            const float h  = (eD - 1.0f) * RCPF((1.0f + eE) * (eD + 1.0f));
            o1B = fmaf(h, wl, o1B);
        }
    }

    // ---- reduce over j: 16 lanes (m) in-wave, then 4 waves via LDS ----
    float v0A = o0A, v0B = o0B, v1A = o1A, v1B = o1B;
    #pragma unroll
    for (int off = 1; off < 16; off <<= 1) {
        v0A += __shfl_xor(v0A, off, 64);
        v0B += __shfl_xor(v0B, off, 64);
        v1A += __shfl_xor(v1A, off, 64);
        v1B += __shfl_xor(v1B, off, 64);
    }
    if (m == 0) {
        out_part[w][r0A] = v0A;
        out_part[w][r0B] = v0B;
        out_part[w][r1A] = v1A;
        out_part[w][r1B] = v1B;
    }
    __syncthreads();
    if (tid < BT) {
        out[b0 + tid] = out_part[0][tid] + out_part[1][tid]
                      + out_part[2][tid] + out_part[3][tid] + b_lin[0];
    }
}

extern "C" void kernel_launch(void* const* d_in, const int* in_sizes, int n_in,
                              void* d_out, int out_size, void* d_ws, size_t ws_size,
                              hipStream_t stream) {
    const float* x     = (const float*)d_in[0];
    const float* W_ih  = (const float*)d_in[1];
    const float* W_hh  = (const float*)d_in[2];
    const float* b_ih  = (const float*)d_in[3];
    const float* b_hh  = (const float*)d_in[4];
    const float* W_lin = (const float*)d_in[5];
    const float* b_lin = (const float*)d_in[6];
    float* out = (float*)d_out;

    dim3 grid(NBLK);
    dim3 block(256);
    qlstm_v17<<<grid, block, 0, stream>>>(x, W_ih, W_hh, b_ih, b_hh,
                                          W_lin, b_lin, out);
}

// Round 18
// 89.316 us; speedup vs baseline: 1.5317x; 1.5317x over previous
//
#include <hip/hip_runtime.h>

#define SEQ 200
#define HID 64
#define BT  8
#define NBLK (4096 / BT)   // 512 blocks -> 2 per CU, 2 waves/SIMD

typedef _Float16 f16;
typedef _Float16 f16x8 __attribute__((ext_vector_type(8)));
typedef float    f32x4 __attribute__((ext_vector_type(4)));

#define LOG2E 1.44269504088896340736f

#if __has_builtin(__builtin_amdgcn_exp2f)
#define EXP2F(x) __builtin_amdgcn_exp2f(x)
#else
#define EXP2F(x) __expf(0.69314718056f * (x))
#endif
#define RCPF(x) __builtin_amdgcn_rcpf(x)

// R14 base (proven 84.5us) + three audited deltas:
//  1. MFMA C-in = bias ONLY (register constant) -> MFMA issues the moment the
//     A-frags land; x*W_ih folded into the pointwise as fmaf(x,wih,acc)
//     (same op count, off the post-barrier critical path).
//  2. t2s*(eB-1) -> fmaf(t2s, eB, -t2s): one op saved per cell.
//  3. Phase-skew probe: the block pair sharing a CU (differs in blockIdx bit 8
//     under round-robin dispatch) is offset by ~half a step via s_sleep(8)
//     before the loop -- breaks potential phase-locking of the two resident
//     waves per SIMD. Pure timing; zero correctness surface.
// Everything else byte-identical to R14: sigma-row mapping (frag row r holds
// batch 2*(r>>2)+(r&1); lane group a reads cells (2a,j),(2a+1,j) from C regs
// 0,1), shared-rcp trans (5 exp + 3 rcp/cell), single h-write per cell (rows
// 4a,4a+1; rows 4a+2,3 stay zero), setprio span, one barrier/step, XOR-swizzled
// dbuf h, W_lin f32 in LDS.
__global__ __launch_bounds__(256, 2)
void qlstm_v18(const float* __restrict__ x,      // [4096, 200]
               const float* __restrict__ W_ih,   // [256]
               const float* __restrict__ W_hh,   // [256, 64]
               const float* __restrict__ b_ih,   // [256]
               const float* __restrict__ b_hh,   // [256]
               const float* __restrict__ W_lin,  // [200*64]
               const float* __restrict__ b_lin,  // [1]
               float* __restrict__ out)          // [4096]
{
    __shared__ float x_lds[BT][201];        // 6.3 KB
    __shared__ f16   h_frag[2][16 * HID];   // 4 KB dbuf, swizzled frag layout
    __shared__ float wl_lds[SEQ * HID];     // 51.2 KB
    __shared__ float out_part[4][BT];

    const int tid = threadIdx.x;
    const int w   = tid >> 6;     // wave: j-block owner
    const int l   = tid & 63;
    const int m   = l & 15;       // B col / C col
    const int a   = l >> 4;       // k-group / C row-group
    const int b0  = blockIdx.x * BT;

    // quadrant pre-scales: i,f,o -> log2e ; g -> 2*log2e
    const float qs[4] = {LOG2E, LOG2E, 2.0f * LOG2E, LOG2E};

    // ---- stage x rows 0..7 (f32, coalesced) ----
    for (int i = tid; i < BT * SEQ; i += 256) {
        int b = i / SEQ, t = i - b * SEQ;
        x_lds[b][t] = x[(size_t)b0 * SEQ + i];
    }
    // ---- stage W_lin (float4) ----
    {
        const float4* src = (const float4*)W_lin;
        float4* dst = (float4*)wl_lds;
        for (int i = tid; i < SEQ * HID / 4; i += 256) dst[i] = src[i];
    }
    // ---- zero both h buffers (rows == 2,3 mod 4 stay zero forever) ----
    for (int i = tid; i < 1024; i += 256) ((float*)h_frag)[i] = 0.0f;

    // ---- B fragments (W_hh^T, pre-scaled) once: col n=q*64+16w+m, k=kk*32+a*8+e ----
    f16x8 Bf[4][2];
    float wihq[4], biasq[4];
    #pragma unroll
    for (int q = 0; q < 4; ++q) {
        const int n = q * 64 + w * 16 + m;
        wihq[q]  = W_ih[n] * qs[q];
        biasq[q] = (b_ih[n] + b_hh[n]) * qs[q];
        #pragma unroll
        for (int kk = 0; kk < 2; ++kk) {
            const float4* p = (const float4*)(W_hh + n * HID + kk * 32 + a * 8);
            float4 lo = p[0], hi = p[1];
            f16x8 f;
            f[0] = (f16)(lo.x * qs[q]); f[1] = (f16)(lo.y * qs[q]);
            f[2] = (f16)(lo.z * qs[q]); f[3] = (f16)(lo.w * qs[q]);
            f[4] = (f16)(hi.x * qs[q]); f[5] = (f16)(hi.y * qs[q]);
            f[6] = (f16)(hi.z * qs[q]); f[7] = (f16)(hi.w * qs[q]);
            Bf[q][kk] = f;
        }
    }

    const int jpw = w * 16 + m;
    // A-frag read addrs: row m, slot s=kk*4+a, byte = m*128 + ((s^(m&7))<<4)
    const int ra0 = m * 128 + (((0 + a) ^ (m & 7)) << 4);
    const int ra1 = m * 128 + (((4 + a) ^ (m & 7)) << 4);
    // this lane's two batch rows (direct from C regs 0,1 -- no merge)
    const int bA = 2 * a;
    const int bB = 2 * a + 1;
    // h write addrs: ONLY rows 4a (batch bA) and 4a+1 (batch bB) are consumed.
    const int R0 = 4 * a, R1 = 4 * a + 1;
    const int hwA = R0 * 128 + (((jpw >> 3) ^ (R0 & 7)) << 4) + (jpw & 7) * 2;
    const int hwB = R1 * 128 + (((jpw >> 3) ^ (R1 & 7)) << 4) + (jpw & 7) * 2;

    const char* hbytes = (const char*)h_frag;

    float cA = 0.0f, cB = 0.0f, oA = 0.0f, oB = 0.0f;
    const float t2s = 2.0f * LOG2E;

    __syncthreads();

    // Phase-skew: the CU-sharing partner block (differs in bit 8 of blockIdx
    // under round-robin dispatch) starts ~half a step later. Timing-only.
    if ((blockIdx.x >> 8) & 1)
        __builtin_amdgcn_s_sleep(8);

    for (int t = 0; t < SEQ; ++t) {
        const int rb = (t & 1) << 11;   // read-buffer byte offset
        const int wb = rb ^ 2048;       // write-buffer byte offset

        // ======== gate GEMM (C-in = bias only; x*W_ih folded post-MFMA) ========
        __builtin_amdgcn_s_setprio(1);
        const f16x8 A0 = *(const f16x8*)(hbytes + rb + ra0);
        const f16x8 A1 = *(const f16x8*)(hbytes + rb + ra1);
        const float x0 = x_lds[bA][t];
        const float x1 = x_lds[bB][t];
        const float wl = wl_lds[t * HID + jpw];

        f32x4 acc[4];
        #pragma unroll
        for (int q = 0; q < 4; ++q) {
            f32x4 ini;
            ini[0] = biasq[q]; ini[1] = biasq[q];
            ini[2] = biasq[q]; ini[3] = biasq[q];
            f32x4 z = __builtin_amdgcn_mfma_f32_16x16x32_f16(A0, Bf[q][0], ini, 0, 0, 0);
            acc[q]  = __builtin_amdgcn_mfma_f32_16x16x32_f16(A1, Bf[q][1], z, 0, 0, 0);
        }
        __builtin_amdgcn_s_setprio(0);

        // ======== pointwise: two cells per thread, shared-rcp trans ========
        {
            const float s0 = fmaf(x0, wihq[0], acc[0][0]);
            const float s1 = fmaf(x0, wihq[1], acc[1][0]);
            const float s2 = fmaf(x0, wihq[2], acc[2][0]);
            const float s3 = fmaf(x0, wihq[3], acc[3][0]);
            const float eA = EXP2F(-s0);
            const float eC = EXP2F(-s1);
            const float eB = EXP2F(s2);
            const float eE = EXP2F(-s3);
            const float ig = fmaf(t2s, eB, -t2s) * RCPF((1.0f + eA) * (eB + 1.0f));
            const float gf = RCPF(1.0f + eC);
            cA = fmaf(gf, cA, ig);                // cA pre-scaled by 2*log2e
            const float eD = EXP2F(cA);
            const float h  = (eD - 1.0f) * RCPF((1.0f + eE) * (eD + 1.0f));
            *(f16*)((char*)h_frag + wb + hwA) = (f16)h;
            oA = fmaf(h, wl, oA);
        }
        {
            const float s0 = fmaf(x1, wihq[0], acc[0][1]);
            const float s1 = fmaf(x1, wihq[1], acc[1][1]);
            const float s2 = fmaf(x1, wihq[2], acc[2][1]);
            const float s3 = fmaf(x1, wihq[3], acc[3][1]);
            const float eA = EXP2F(-s0);
            const float eC = EXP2F(-s1);
            const float eB = EXP2F(s2);
            const float eE = EXP2F(-s3);
            const float ig = fmaf(t2s, eB, -t2s) * RCPF((1.0f + eA) * (eB + 1.0f));
            const float gf = RCPF(1.0f + eC);
            cB = fmaf(gf, cB, ig);
            const float eD = EXP2F(cB);
            const float h  = (eD - 1.0f) * RCPF((1.0f + eE) * (eD + 1.0f));
            *(f16*)((char*)h_frag + wb + hwB) = (f16)h;
            oB = fmaf(h, wl, oB);
        }

        __syncthreads();   // h(write-buf) complete -> next step reads it
    }

    // ---- reduce over j: 16 lanes (m) in-wave, then 4 waves via LDS ----
    float vA = oA, vB = oB;
    #pragma unroll
    for (int off = 1; off < 16; off <<= 1) {
        vA += __shfl_xor(vA, off, 64);
        vB += __shfl_xor(vB, off, 64);
    }
    if (m == 0) {
        out_part[w][bA] = vA;
        out_part[w][bB] = vB;
    }
    __syncthreads();
    if (tid < BT) {
        out[b0 + tid] = out_part[0][tid] + out_part[1][tid]
                      + out_part[2][tid] + out_part[3][tid] + b_lin[0];
    }
}

extern "C" void kernel_launch(void* const* d_in, const int* in_sizes, int n_in,
                              void* d_out, int out_size, void* d_ws, size_t ws_size,
                              hipStream_t stream) {
    const float* x     = (const float*)d_in[0];
    const float* W_ih  = (const float*)d_in[1];
    const float* W_hh  = (const float*)d_in[2];
    const float* b_ih  = (const float*)d_in[3];
    const float* b_hh  = (const float*)d_in[4];
    const float* W_lin = (const float*)d_in[5];
    const float* b_lin = (const float*)d_in[6];
    float* out = (float*)d_out;

    dim3 grid(NBLK);
    dim3 block(256);
    qlstm_v18<<<grid, block, 0, stream>>>(x, W_ih, W_hh, b_ih, b_hh,
                                          W_lin, b_lin, out);
}